// Round 10
// baseline (107.293 us; speedup 1.0000x reference)
//
#include <hip/hip_runtime.h>
#include <hip/hip_bf16.h>
#include <cstdint>

// PiNet: B=8192, I=12, O=512, DEG=4.
// R9: t-space re-laid out block-by-prefix, every block padded to x4 so each
// aligned quad = {shared off1} x {4 consecutive off2}. T = 2108 -> TPAD 2112.
// Gen = 5 ds_read_b32 per quad, branch-free. Gemm: 512 blocks x 512 thr
// (2/CU), wave 16b x 64o. Fold: f32 LDS staging + orbit gather (per R6).

#define NB 8192
#define NI 12
#define NO 512
#define TPAD 2112          // 33 * 64
#define NKT 33
#define NOCT 264           // TPAD / 8
#define NQ 528             // TPAD / 4

typedef __attribute__((ext_vector_type(8))) _Float16 f16x8;
typedef __attribute__((ext_vector_type(4))) float f32x4;

#define MFMA16(a, b, c) __builtin_amdgcn_mfma_f32_16x16x32_f16(a, b, c, 0, 0, 0)

__device__ __forceinline__ int ceil4(int n) { return (n + 3) & ~3; }
__device__ __forceinline__ int H2f(int n) { return n * (n + 1) / 2; }
__device__ __forceinline__ int rank2(int a, int b) {
    int r = 0;
    for (int j = 0; j < a; ++j) r += NI - j;
    return r + (b - a);
}
__device__ __forceinline__ unsigned short f2h(float f) {
    _Float16 h = (_Float16)f;
    return __builtin_bit_cast(unsigned short, h);
}

// Layout bases: [0,16) deg<=1; [16,112) deg2; [112,608) deg3; [608,2108) deg4.
#define BASE2 16
#define BASE3 112
#define BASE4 608
#define TEND 2108

// ---------- maps: fd/rkA (fold descriptors), qd (gen quads), mq2 (msm pairs) --
__global__ __launch_bounds__(256) void pinet_maps(
    uint32_t* __restrict__ fd, float* __restrict__ rkA,
    uint32_t* __restrict__ qd, uint32_t* __restrict__ mq2) {
    int id = blockIdx.x * 256 + threadIdx.x;
    if (id < TPAD) {
        int t = id;
        uint32_t f = 7u << 16; float rk = 0.0f;
        if (t == 0) { f = 0u; rk = 1.0f; }
        else if (t < 13) { f = (1u << 16) | (uint32_t)(t - 1); rk = 1.0f; }
        else if (t < BASE2) { /* pad */ }
        else if (t < BASE3) {
            int base = BASE2;
            for (int a = 0; a < 12; ++a) {
                int L = ceil4(12 - a);
                if (t < base + L) {
                    int p = t - base;
                    if (p < 12 - a) {
                        int b = a + p;
                        f = (2u << 16) | (uint32_t)a | ((uint32_t)b << 4);
                        rk = (a == b) ? 0.5f : 1.0f;
                    }
                    break;
                }
                base += L;
            }
        } else if (t < BASE4) {
            int base = BASE3; bool done = false;
            for (int a = 0; a < 12 && !done; ++a)
                for (int b = a; b < 12; ++b) {
                    int L = ceil4(12 - b);
                    if (t < base + L) {
                        int p = t - base;
                        if (p < 12 - b) {
                            int c = b + p;
                            f = (3u << 16) | (uint32_t)a | ((uint32_t)b << 4) |
                                ((uint32_t)c << 8);
                            int k = 1, run = 1;
                            if (b == a) { ++run; k *= run; } else run = 1;
                            if (c == b) { ++run; k *= run; } else run = 1;
                            rk = 1.0f / (float)k;
                        }
                        done = true; break;
                    }
                    base += L;
                }
        } else if (t < TEND) {
            int base = BASE4; bool done = false;
            for (int a = 0; a < 12 && !done; ++a)
                for (int b = a; b < 12; ++b) {
                    int L = ceil4(H2f(12 - b));
                    if (t < base + L) {
                        int p = t - base;
                        if (p < H2f(12 - b)) {
                            int c = b;
                            while (p >= 12 - c) { p -= 12 - c; ++c; }
                            int d = c + p;
                            f = (4u << 16) | (uint32_t)a | ((uint32_t)b << 4) |
                                ((uint32_t)c << 8) | ((uint32_t)d << 12);
                            int k = 1, run = 1;
                            if (b == a) { ++run; k *= run; } else run = 1;
                            if (c == b) { ++run; k *= run; } else run = 1;
                            if (d == c) { ++run; k *= run; } else run = 1;
                            rk = 1.0f / (float)k;
                        }
                        done = true; break;
                    }
                    base += L;
                }
        }
        fd[t] = f; rkA[t] = rk;
        return;
    }
    id -= TPAD;
    if (id < NQ) {                       // quad descriptors: off1 | off2_0<<8
        int t0 = id * 4;
        uint32_t o1 = 0, o2 = 0;
        if (t0 < 16) {
            o1 = 0; o2 = (uint32_t)t0;
        } else if (t0 < BASE3) {
            int base = BASE2;
            for (int a = 0; a < 12; ++a) {
                int L = ceil4(12 - a);
                if (t0 < base + L) { o1 = 1 + a; o2 = 1 + a + (t0 - base); break; }
                base += L;
            }
        } else if (t0 < BASE4) {
            int base = BASE3; bool done = false;
            for (int a = 0; a < 12 && !done; ++a)
                for (int b = a; b < 12; ++b) {
                    int L = ceil4(12 - b);
                    if (t0 < base + L) {
                        o1 = 13 + rank2(a, b); o2 = 1 + b + (t0 - base);
                        done = true; break;
                    }
                    base += L;
                }
        } else if (t0 < TEND) {
            int base = BASE4; bool done = false;
            for (int a = 0; a < 12 && !done; ++a)
                for (int b = a; b < 12; ++b) {
                    int L = ceil4(H2f(12 - b));
                    if (t0 < base + L) {
                        o1 = 13 + rank2(a, b);
                        o2 = 13 + rank2(b, b) + (t0 - base);
                        done = true; break;
                    }
                    base += L;
                }
        }
        qd[id] = o1 | (o2 << 8);
        return;
    }
    id -= NQ;
    if (id < 78) {                       // deg2 msm build pairs
        int r = id;
        int a = 0; while (r >= (NI - a)) { r -= (NI - a); ++a; }
        int b = a + r;
        mq2[id] = (uint32_t)(1 + a) | ((uint32_t)(1 + b) << 16);
    }
}

// ---------- fold: stage weight row in LDS (f32), per-t orbit gather ----------
// One block (1024 threads) per o. Wh fp16 pack-of-8: [((t>>3)*512+o)*8+(t&7)].
__global__ __launch_bounds__(1024) void pinet_fold(
    const float* __restrict__ w0, const float* __restrict__ w1,
    const float* __restrict__ w2, const float* __restrict__ w3,
    const float* __restrict__ w4,
    const uint32_t* __restrict__ fd, const float* __restrict__ rkA,
    ushort* __restrict__ Wh) {
    __shared__ float sw4[20736];
    __shared__ float sw3[1728];
    __shared__ float sw2[144];
    const int tid = threadIdx.x;
    const int o = blockIdx.x;

    {   // coalesced staging
        const float4* g4 = (const float4*)(w4 + o * 20736);
        float4* s4 = (float4*)sw4;
        for (int i = tid; i < 5184; i += 1024) s4[i] = g4[i];
        if (tid < 432) ((float4*)sw3)[tid] = ((const float4*)(w3 + o * 1728))[tid];
        if (tid < 36)  ((float4*)sw2)[tid] = ((const float4*)(w2 + o * 144))[tid];
    }
    __syncthreads();

#define W4P(p, q, r, s_) sw4[(p) * 1728 + (q) * 144 + (r) * 12 + (s_)]
#define W3P(p, q, r)     sw3[(p) * 144 + (q) * 12 + (r)]
    for (int t = tid; t < TPAD; t += 1024) {
        uint32_t f = fd[t];
        int deg = (f >> 16) & 7;
        int a = f & 15, b = (f >> 4) & 15, c = (f >> 8) & 15, d = (f >> 12) & 15;
        float s = 0.0f;
        if (deg == 0) {
            s = w0[o];
        } else if (deg == 1) {
            s = w1[o * 12 + a];
        } else if (deg == 2) {
            s = (sw2[a * 12 + b] + sw2[b * 12 + a]) * rkA[t];
        } else if (deg == 3) {
            s = (W3P(a, b, c) + W3P(a, c, b) + W3P(b, a, c) +
                 W3P(b, c, a) + W3P(c, a, b) + W3P(c, b, a)) * rkA[t];
        } else if (deg == 4) {
            float s4v =
                W4P(a,b,c,d) + W4P(a,b,d,c) + W4P(a,c,b,d) + W4P(a,c,d,b) +
                W4P(a,d,b,c) + W4P(a,d,c,b) + W4P(b,a,c,d) + W4P(b,a,d,c) +
                W4P(b,c,a,d) + W4P(b,c,d,a) + W4P(b,d,a,c) + W4P(b,d,c,a) +
                W4P(c,a,b,d) + W4P(c,a,d,b) + W4P(c,b,a,d) + W4P(c,b,d,a) +
                W4P(c,d,a,b) + W4P(c,d,b,a) + W4P(d,a,b,c) + W4P(d,a,c,b) +
                W4P(d,b,a,c) + W4P(d,b,c,a) + W4P(d,c,a,b) + W4P(d,c,b,a);
            s = s4v * rkA[t];
        }
        Wh[((t >> 3) * NO + o) * 8 + (t & 7)] = f2h(s);
    }
#undef W4P
#undef W3P
}

// ---------- MFMA GEMM: out[b,o] = sum_t M[t][b] * Wt[t][o], fp16 ----------
// Block: 32 b x 256 o, 512 threads (8 waves = 2wB x 4wO), wave 16b x 64o.
// Grid 512 -> 2 blocks/CU (independent barrier domains). Gen: 5 b32/quad.
__global__ __launch_bounds__(512, 4) void pinet_gemm(
    const float* __restrict__ x, const ushort* __restrict__ Wh,
    const uint32_t* __restrict__ qd, const uint32_t* __restrict__ mq2,
    float* __restrict__ out) {
    __shared__ float msm[32 * 97];        // per-b {1, x0..x11, 78 deg2, 6 zero}
    __shared__ ushort Ash[2][32][8][8];   // [buf][b][t-oct slot (swz)][8 fp16]
    __shared__ uint32_t qd_sh[NQ];

    const int tid = threadIdx.x;
    const int b0 = (blockIdx.x >> 1) * 32;
    const int blkO = blockIdx.x & 1;

    // phase 1: constants, x, zero-pad
    for (int idx = tid; idx < 32 * 12; idx += 512) {
        int b = idx / 12, j = idx % 12;
        msm[b * 97 + 1 + j] = x[(b0 + b) * 12 + j];
    }
    if (tid < 32) msm[tid * 97] = 1.0f;
    for (int idx = tid; idx < 32 * 6; idx += 512) {
        int b = idx / 6, j = idx % 6;
        msm[b * 97 + 91 + j] = 0.0f;
    }
    for (int i = tid; i < NQ; i += 512) qd_sh[i] = qd[i];
    __syncthreads();
    // phase 2: deg2 products
    for (int idx = tid; idx < 32 * 78; idx += 512) {
        int b = idx / 78, q = idx % 78;
        uint32_t m2 = mq2[q];
        msm[b * 97 + 13 + q] = msm[b * 97 + (m2 & 0xFFFFu)] *
                               msm[b * 97 + (m2 >> 16)];
    }

    const int l = tid & 63, wv = tid >> 6;
    const int lm = l & 15, lg = l >> 4;
    const int wB = wv >> 2, wO = wv & 3;
    const int o_w = blkO * 256 + wO * 64;
    const int gb = tid & 31, qs = tid >> 5;      // gen role: b x quad-slot
    const int br = wB * 16 + lm;                 // A-read row

    f32x4 acc[4] = {};

    auto gen = [&](int kt, int buf) {
        uint32_t dsc = qd_sh[kt * 16 + qs];
        int o1 = dsc & 0xFFu, o2 = (dsc >> 8) & 0xFFu;
        const float* row = &msm[gb * 97];
        float m1 = row[o1];
        float p0 = m1 * row[o2 + 0];
        float p1 = m1 * row[o2 + 1];
        float p2 = m1 * row[o2 + 2];
        float p3 = m1 * row[o2 + 3];
        ushort4 v = {f2h(p0), f2h(p1), f2h(p2), f2h(p3)};
        *(ushort4*)&Ash[buf][gb][(qs >> 1) ^ (gb & 7)][(qs & 1) * 4] = v;
    };

    __syncthreads();          // msm ready
    gen(0, 0);
    __syncthreads();          // Ash[0] ready

    for (int kt = 0; kt < NKT; ++kt) {
        const int buf = kt & 1;
        if (kt + 1 < NKT) gen(kt + 1, buf ^ 1);

        f16x8 Bv[2][4];
#pragma unroll
        for (int c = 0; c < 2; ++c)
#pragma unroll
            for (int os = 0; os < 4; ++os) {
                int pk = kt * 8 + c * 4 + lg;
                Bv[c][os] = *(const f16x8*)
                    (Wh + ((size_t)pk * NO + o_w + os * 16 + lm) * 8);
            }
#pragma unroll
        for (int c = 0; c < 2; ++c) {
            f16x8 a = *(const f16x8*)&Ash[buf][br][(c * 4 + lg) ^ (br & 7)][0];
#pragma unroll
            for (int os = 0; os < 4; ++os)
                acc[os] = MFMA16(a, Bv[c][os], acc[os]);
        }
        __syncthreads();
    }

#pragma unroll
    for (int os = 0; os < 4; ++os) {
        int ob = o_w + os * 16 + lm;
#pragma unroll
        for (int r = 0; r < 4; ++r) {
            int bb = b0 + wB * 16 + lg * 4 + r;
            out[bb * NO + ob] = acc[os][r];
        }
    }
}

extern "C" void kernel_launch(void* const* d_in, const int* in_sizes, int n_in,
                              void* d_out, int out_size, void* d_ws, size_t ws_size,
                              hipStream_t stream) {
    const float* x  = (const float*)d_in[0];
    const float* w0 = (const float*)d_in[1];
    const float* w1 = (const float*)d_in[2];
    const float* w2 = (const float*)d_in[3];
    const float* w3 = (const float*)d_in[4];
    const float* w4 = (const float*)d_in[5];
    float* out = (float*)d_out;

    uint8_t* ws = (uint8_t*)d_ws;
    uint32_t* qd  = (uint32_t*)ws;                 // 2112 B  (pad 4096)
    uint32_t* mq2 = (uint32_t*)(ws + 4096);        // 312 B   (pad 512)
    uint32_t* fd  = (uint32_t*)(ws + 4608);        // 8448 B  (pad 8704)
    float*    rkA = (float*)(ws + 13312);          // 8448 B  (pad 8704)
    ushort*   Wh  = (ushort*)(ws + 22016);         // 264*512*8*2 = 2,162,688 B

    pinet_maps<<<11, 256, 0, stream>>>(fd, rkA, qd, mq2);
    pinet_fold<<<NO, 1024, 0, stream>>>(w0, w1, w2, w3, w4, fd, rkA, Wh);
    pinet_gemm<<<(NB / 32) * 2, 512, 0, stream>>>(x, Wh, qd, mq2, out);
}

// Round 11
// 62.121 us; speedup vs baseline: 1.7272x; 1.7272x over previous
//
#include <hip/hip_runtime.h>
#include <hip/hip_bf16.h>
#include <cstdint>

// PiNet: B=8192, I=12, O=512, DEG=4.
// R10: R9's padded-prefix t-layout + quad-gen kept; gemm geometry restored to
// R6's optimum: block 64b x 256o, 512 thr (8 waves = 2wB x 4wO), wave 32b x 64o,
// KT=64, B-regs double-buffered, one barrier per kt. Fold/maps unchanged.

#define NB 8192
#define NI 12
#define NO 512
#define TPAD 2112          // 33 * 64
#define NKT 33
#define NQ 528             // TPAD / 4

typedef __attribute__((ext_vector_type(8))) _Float16 f16x8;
typedef __attribute__((ext_vector_type(4))) float f32x4;

#define MFMA16(a, b, c) __builtin_amdgcn_mfma_f32_16x16x32_f16(a, b, c, 0, 0, 0)

__device__ __forceinline__ int ceil4(int n) { return (n + 3) & ~3; }
__device__ __forceinline__ int H2f(int n) { return n * (n + 1) / 2; }
__device__ __forceinline__ int rank2(int a, int b) {
    int r = 0;
    for (int j = 0; j < a; ++j) r += NI - j;
    return r + (b - a);
}
__device__ __forceinline__ unsigned short f2h(float f) {
    _Float16 h = (_Float16)f;
    return __builtin_bit_cast(unsigned short, h);
}

// Layout bases: [0,16) deg<=1; [16,112) deg2; [112,608) deg3; [608,2108) deg4.
#define BASE2 16
#define BASE3 112
#define BASE4 608
#define TEND 2108

// ---------- maps: fd/rkA (fold descriptors), qd (gen quads), mq2 (msm pairs) --
__global__ __launch_bounds__(256) void pinet_maps(
    uint32_t* __restrict__ fd, float* __restrict__ rkA,
    uint32_t* __restrict__ qd, uint32_t* __restrict__ mq2) {
    int id = blockIdx.x * 256 + threadIdx.x;
    if (id < TPAD) {
        int t = id;
        uint32_t f = 7u << 16; float rk = 0.0f;
        if (t == 0) { f = 0u; rk = 1.0f; }
        else if (t < 13) { f = (1u << 16) | (uint32_t)(t - 1); rk = 1.0f; }
        else if (t < BASE2) { /* pad */ }
        else if (t < BASE3) {
            int base = BASE2;
            for (int a = 0; a < 12; ++a) {
                int L = ceil4(12 - a);
                if (t < base + L) {
                    int p = t - base;
                    if (p < 12 - a) {
                        int b = a + p;
                        f = (2u << 16) | (uint32_t)a | ((uint32_t)b << 4);
                        rk = (a == b) ? 0.5f : 1.0f;
                    }
                    break;
                }
                base += L;
            }
        } else if (t < BASE4) {
            int base = BASE3; bool done = false;
            for (int a = 0; a < 12 && !done; ++a)
                for (int b = a; b < 12; ++b) {
                    int L = ceil4(12 - b);
                    if (t < base + L) {
                        int p = t - base;
                        if (p < 12 - b) {
                            int c = b + p;
                            f = (3u << 16) | (uint32_t)a | ((uint32_t)b << 4) |
                                ((uint32_t)c << 8);
                            int k = 1, run = 1;
                            if (b == a) { ++run; k *= run; } else run = 1;
                            if (c == b) { ++run; k *= run; } else run = 1;
                            rk = 1.0f / (float)k;
                        }
                        done = true; break;
                    }
                    base += L;
                }
        } else if (t < TEND) {
            int base = BASE4; bool done = false;
            for (int a = 0; a < 12 && !done; ++a)
                for (int b = a; b < 12; ++b) {
                    int L = ceil4(H2f(12 - b));
                    if (t < base + L) {
                        int p = t - base;
                        if (p < H2f(12 - b)) {
                            int c = b;
                            while (p >= 12 - c) { p -= 12 - c; ++c; }
                            int d = c + p;
                            f = (4u << 16) | (uint32_t)a | ((uint32_t)b << 4) |
                                ((uint32_t)c << 8) | ((uint32_t)d << 12);
                            int k = 1, run = 1;
                            if (b == a) { ++run; k *= run; } else run = 1;
                            if (c == b) { ++run; k *= run; } else run = 1;
                            if (d == c) { ++run; k *= run; } else run = 1;
                            rk = 1.0f / (float)k;
                        }
                        done = true; break;
                    }
                    base += L;
                }
        }
        fd[t] = f; rkA[t] = rk;
        return;
    }
    id -= TPAD;
    if (id < NQ) {                       // quad descriptors: off1 | off2_0<<8
        int t0 = id * 4;
        uint32_t o1 = 0, o2 = 0;
        if (t0 < 16) {
            o1 = 0; o2 = (uint32_t)t0;
        } else if (t0 < BASE3) {
            int base = BASE2;
            for (int a = 0; a < 12; ++a) {
                int L = ceil4(12 - a);
                if (t0 < base + L) { o1 = 1 + a; o2 = 1 + a + (t0 - base); break; }
                base += L;
            }
        } else if (t0 < BASE4) {
            int base = BASE3; bool done = false;
            for (int a = 0; a < 12 && !done; ++a)
                for (int b = a; b < 12; ++b) {
                    int L = ceil4(12 - b);
                    if (t0 < base + L) {
                        o1 = 13 + rank2(a, b); o2 = 1 + b + (t0 - base);
                        done = true; break;
                    }
                    base += L;
                }
        } else if (t0 < TEND) {
            int base = BASE4; bool done = false;
            for (int a = 0; a < 12 && !done; ++a)
                for (int b = a; b < 12; ++b) {
                    int L = ceil4(H2f(12 - b));
                    if (t0 < base + L) {
                        o1 = 13 + rank2(a, b);
                        o2 = 13 + rank2(b, b) + (t0 - base);
                        done = true; break;
                    }
                    base += L;
                }
        }
        qd[id] = o1 | (o2 << 8);
        return;
    }
    id -= NQ;
    if (id < 78) {                       // deg2 msm build pairs
        int r = id;
        int a = 0; while (r >= (NI - a)) { r -= (NI - a); ++a; }
        int b = a + r;
        mq2[id] = (uint32_t)(1 + a) | ((uint32_t)(1 + b) << 16);
    }
}

// ---------- fold: stage weight row in LDS (f32), per-t orbit gather ----------
// One block (1024 threads) per o. Wh fp16 pack-of-8: [((t>>3)*512+o)*8+(t&7)].
__global__ __launch_bounds__(1024) void pinet_fold(
    const float* __restrict__ w0, const float* __restrict__ w1,
    const float* __restrict__ w2, const float* __restrict__ w3,
    const float* __restrict__ w4,
    const uint32_t* __restrict__ fd, const float* __restrict__ rkA,
    ushort* __restrict__ Wh) {
    __shared__ float sw4[20736];
    __shared__ float sw3[1728];
    __shared__ float sw2[144];
    const int tid = threadIdx.x;
    const int o = blockIdx.x;

    {   // coalesced staging
        const float4* g4 = (const float4*)(w4 + o * 20736);
        float4* s4 = (float4*)sw4;
        for (int i = tid; i < 5184; i += 1024) s4[i] = g4[i];
        if (tid < 432) ((float4*)sw3)[tid] = ((const float4*)(w3 + o * 1728))[tid];
        if (tid < 36)  ((float4*)sw2)[tid] = ((const float4*)(w2 + o * 144))[tid];
    }
    __syncthreads();

#define W4P(p, q, r, s_) sw4[(p) * 1728 + (q) * 144 + (r) * 12 + (s_)]
#define W3P(p, q, r)     sw3[(p) * 144 + (q) * 12 + (r)]
    for (int t = tid; t < TPAD; t += 1024) {
        uint32_t f = fd[t];
        int deg = (f >> 16) & 7;
        int a = f & 15, b = (f >> 4) & 15, c = (f >> 8) & 15, d = (f >> 12) & 15;
        float s = 0.0f;
        if (deg == 0) {
            s = w0[o];
        } else if (deg == 1) {
            s = w1[o * 12 + a];
        } else if (deg == 2) {
            s = (sw2[a * 12 + b] + sw2[b * 12 + a]) * rkA[t];
        } else if (deg == 3) {
            s = (W3P(a, b, c) + W3P(a, c, b) + W3P(b, a, c) +
                 W3P(b, c, a) + W3P(c, a, b) + W3P(c, b, a)) * rkA[t];
        } else if (deg == 4) {
            float s4v =
                W4P(a,b,c,d) + W4P(a,b,d,c) + W4P(a,c,b,d) + W4P(a,c,d,b) +
                W4P(a,d,b,c) + W4P(a,d,c,b) + W4P(b,a,c,d) + W4P(b,a,d,c) +
                W4P(b,c,a,d) + W4P(b,c,d,a) + W4P(b,d,a,c) + W4P(b,d,c,a) +
                W4P(c,a,b,d) + W4P(c,a,d,b) + W4P(c,b,a,d) + W4P(c,b,d,a) +
                W4P(c,d,a,b) + W4P(c,d,b,a) + W4P(d,a,b,c) + W4P(d,a,c,b) +
                W4P(d,b,a,c) + W4P(d,b,c,a) + W4P(d,c,a,b) + W4P(d,c,b,a);
            s = s4v * rkA[t];
        }
        Wh[((t >> 3) * NO + o) * 8 + (t & 7)] = f2h(s);
    }
#undef W4P
#undef W3P
}

// ---------- MFMA GEMM: out[b,o] = sum_t M[t][b] * Wt[t][o], fp16 ----------
// Block: 64 b x 256 o, 512 threads (8 waves = 2wB x 4wO), wave 32b x 64o, KT=64.
// Gen: 2 quads/thread, 5 b32 each, branch-free; single barrier per kt.
__global__ __launch_bounds__(512, 2) void pinet_gemm(
    const float* __restrict__ x, const ushort* __restrict__ Wh,
    const uint32_t* __restrict__ qd, const uint32_t* __restrict__ mq2,
    float* __restrict__ out) {
    __shared__ float msm[64 * 97];        // per-b {1, x0..x11, 78 deg2, 6 zero}
    __shared__ ushort Ash[2][64][8][8];   // [buf][b][t-oct slot (swz)][8 fp16]
    __shared__ uint32_t qd_sh[NQ];

    const int tid = threadIdx.x;
    const int b0 = (blockIdx.x >> 1) * 64;
    const int blkO = blockIdx.x & 1;

    // phase 1: constants, x, zero-pad
    for (int idx = tid; idx < 64 * 12; idx += 512) {
        int b = idx / 12, j = idx % 12;
        msm[b * 97 + 1 + j] = x[(b0 + b) * 12 + j];
    }
    if (tid < 64) msm[tid * 97] = 1.0f;
    for (int idx = tid; idx < 64 * 6; idx += 512) {
        int b = idx / 6, j = idx % 6;
        msm[b * 97 + 91 + j] = 0.0f;
    }
    for (int i = tid; i < NQ; i += 512) qd_sh[i] = qd[i];
    __syncthreads();
    // phase 2: deg2 products
    for (int idx = tid; idx < 64 * 78; idx += 512) {
        int b = idx / 78, q = idx % 78;
        uint32_t m2 = mq2[q];
        msm[b * 97 + 13 + q] = msm[b * 97 + (m2 & 0xFFFFu)] *
                               msm[b * 97 + (m2 >> 16)];
    }

    const int l = tid & 63, wv = tid >> 6;
    const int lm = l & 15, lg = l >> 4;
    const int wB = wv >> 2, wO = wv & 3;
    const int o_w = blkO * 256 + wO * 64;
    const int gb = tid & 63, qs2 = tid >> 6;     // gen role: b x quad-slot-pair

    f32x4 acc[2][4] = {};                        // [bs][os]
    f16x8 B0[2][4], B1[2][4];                    // [c][os]

    auto gen = [&](int kt, int buf) {
        const float* row = &msm[gb * 97];
#pragma unroll
        for (int jj = 0; jj < 2; ++jj) {
            const int qs = qs2 + jj * 8;         // wave-uniform
            uint32_t dsc = qd_sh[kt * 16 + qs];
            int o1 = dsc & 0xFFu, o2 = (dsc >> 8) & 0xFFu;
            float m1 = row[o1];
            float p0 = m1 * row[o2 + 0];
            float p1 = m1 * row[o2 + 1];
            float p2 = m1 * row[o2 + 2];
            float p3 = m1 * row[o2 + 3];
            ushort4 v = {f2h(p0), f2h(p1), f2h(p2), f2h(p3)};
            *(ushort4*)&Ash[buf][gb][(qs >> 1) ^ (gb & 7)][(qs & 1) * 4] = v;
        }
    };
    auto loadB = [&](int kt, f16x8 (&B)[2][4]) {
#pragma unroll
        for (int c = 0; c < 2; ++c)
#pragma unroll
            for (int os = 0; os < 4; ++os) {
                int pk = kt * 8 + c * 4 + lg;
                B[c][os] = *(const f16x8*)
                    (Wh + ((size_t)pk * NO + o_w + os * 16 + lm) * 8);
            }
    };
    auto mfmaR = [&](int cur, f16x8 (&B)[2][4]) {
#pragma unroll
        for (int c = 0; c < 2; ++c) {
            int br0 = wB * 32 + lm, br1 = wB * 32 + 16 + lm;
            f16x8 a0 = *(const f16x8*)&Ash[cur][br0][(c * 4 + lg) ^ (br0 & 7)][0];
            f16x8 a1 = *(const f16x8*)&Ash[cur][br1][(c * 4 + lg) ^ (br1 & 7)][0];
#pragma unroll
            for (int os = 0; os < 4; ++os) {
                acc[0][os] = MFMA16(a0, B[c][os], acc[0][os]);
                acc[1][os] = MFMA16(a1, B[c][os], acc[1][os]);
            }
        }
    };

    __syncthreads();          // msm ready
    gen(0, 0);
    loadB(0, B0);
    __syncthreads();          // Ash[0] ready

    for (int kt2 = 0; kt2 < NKT - 1; kt2 += 2) {
        loadB(kt2 + 1, B1);
        gen(kt2 + 1, 1);
        mfmaR(0, B0);
        __syncthreads();
        loadB(kt2 + 2, B0);   // kt2+2 <= 32 = NKT-1, always valid
        gen(kt2 + 2, 0);
        mfmaR(1, B1);
        __syncthreads();
    }
    mfmaR(0, B0);             // kt = 32 (buf 0)

#pragma unroll
    for (int bs = 0; bs < 2; ++bs)
#pragma unroll
        for (int os = 0; os < 4; ++os) {
            int ob = o_w + os * 16 + lm;
#pragma unroll
            for (int r = 0; r < 4; ++r) {
                int bb = b0 + wB * 32 + bs * 16 + lg * 4 + r;
                out[bb * NO + ob] = acc[bs][os][r];
            }
        }
}

extern "C" void kernel_launch(void* const* d_in, const int* in_sizes, int n_in,
                              void* d_out, int out_size, void* d_ws, size_t ws_size,
                              hipStream_t stream) {
    const float* x  = (const float*)d_in[0];
    const float* w0 = (const float*)d_in[1];
    const float* w1 = (const float*)d_in[2];
    const float* w2 = (const float*)d_in[3];
    const float* w3 = (const float*)d_in[4];
    const float* w4 = (const float*)d_in[5];
    float* out = (float*)d_out;

    uint8_t* ws = (uint8_t*)d_ws;
    uint32_t* qd  = (uint32_t*)ws;                 // 2112 B  (pad 4096)
    uint32_t* mq2 = (uint32_t*)(ws + 4096);        // 312 B   (pad 512)
    uint32_t* fd  = (uint32_t*)(ws + 4608);        // 8448 B  (pad 8704)
    float*    rkA = (float*)(ws + 13312);          // 8448 B  (pad 8704)
    ushort*   Wh  = (ushort*)(ws + 22016);         // 264*512*8*2 = 2,162,688 B

    pinet_maps<<<11, 256, 0, stream>>>(fd, rkA, qd, mq2);
    pinet_fold<<<NO, 1024, 0, stream>>>(w0, w1, w2, w3, w4, fd, rkA, Wh);
    pinet_gemm<<<(NB / 64) * 2, 512, 0, stream>>>(x, Wh, qd, mq2, out);
}

// Round 12
// 60.932 us; speedup vs baseline: 1.7609x; 1.0195x over previous
//
#include <hip/hip_runtime.h>
#include <hip/hip_bf16.h>
#include <cstdint>

// PiNet: B=8192, I=12, O=512, DEG=4.
// R11: gemm split into 2 independent barrier domains per CU: BB=32, 256 thr
// (4 waves of 32b x 64o, no wB duplication), grid 512 = 2 blocks/CU.
// Aggregate per-CU traffic identical to R10; overlap across domains is the fix.
// Maps / fold / padded-prefix t-layout unchanged from R10.

#define NB 8192
#define NI 12
#define NO 512
#define TPAD 2112          // 33 * 64
#define NKT 33
#define NQ 528             // TPAD / 4

typedef __attribute__((ext_vector_type(8))) _Float16 f16x8;
typedef __attribute__((ext_vector_type(4))) float f32x4;

#define MFMA16(a, b, c) __builtin_amdgcn_mfma_f32_16x16x32_f16(a, b, c, 0, 0, 0)

__device__ __forceinline__ int ceil4(int n) { return (n + 3) & ~3; }
__device__ __forceinline__ int H2f(int n) { return n * (n + 1) / 2; }
__device__ __forceinline__ int rank2(int a, int b) {
    int r = 0;
    for (int j = 0; j < a; ++j) r += NI - j;
    return r + (b - a);
}
__device__ __forceinline__ unsigned short f2h(float f) {
    _Float16 h = (_Float16)f;
    return __builtin_bit_cast(unsigned short, h);
}

// Layout bases: [0,16) deg<=1; [16,112) deg2; [112,608) deg3; [608,2108) deg4.
#define BASE2 16
#define BASE3 112
#define BASE4 608
#define TEND 2108

// ---------- maps: fd/rkA (fold descriptors), qd (gen quads), mq2 (msm pairs) --
__global__ __launch_bounds__(256) void pinet_maps(
    uint32_t* __restrict__ fd, float* __restrict__ rkA,
    uint32_t* __restrict__ qd, uint32_t* __restrict__ mq2) {
    int id = blockIdx.x * 256 + threadIdx.x;
    if (id < TPAD) {
        int t = id;
        uint32_t f = 7u << 16; float rk = 0.0f;
        if (t == 0) { f = 0u; rk = 1.0f; }
        else if (t < 13) { f = (1u << 16) | (uint32_t)(t - 1); rk = 1.0f; }
        else if (t < BASE2) { /* pad */ }
        else if (t < BASE3) {
            int base = BASE2;
            for (int a = 0; a < 12; ++a) {
                int L = ceil4(12 - a);
                if (t < base + L) {
                    int p = t - base;
                    if (p < 12 - a) {
                        int b = a + p;
                        f = (2u << 16) | (uint32_t)a | ((uint32_t)b << 4);
                        rk = (a == b) ? 0.5f : 1.0f;
                    }
                    break;
                }
                base += L;
            }
        } else if (t < BASE4) {
            int base = BASE3; bool done = false;
            for (int a = 0; a < 12 && !done; ++a)
                for (int b = a; b < 12; ++b) {
                    int L = ceil4(12 - b);
                    if (t < base + L) {
                        int p = t - base;
                        if (p < 12 - b) {
                            int c = b + p;
                            f = (3u << 16) | (uint32_t)a | ((uint32_t)b << 4) |
                                ((uint32_t)c << 8);
                            int k = 1, run = 1;
                            if (b == a) { ++run; k *= run; } else run = 1;
                            if (c == b) { ++run; k *= run; } else run = 1;
                            rk = 1.0f / (float)k;
                        }
                        done = true; break;
                    }
                    base += L;
                }
        } else if (t < TEND) {
            int base = BASE4; bool done = false;
            for (int a = 0; a < 12 && !done; ++a)
                for (int b = a; b < 12; ++b) {
                    int L = ceil4(H2f(12 - b));
                    if (t < base + L) {
                        int p = t - base;
                        if (p < H2f(12 - b)) {
                            int c = b;
                            while (p >= 12 - c) { p -= 12 - c; ++c; }
                            int d = c + p;
                            f = (4u << 16) | (uint32_t)a | ((uint32_t)b << 4) |
                                ((uint32_t)c << 8) | ((uint32_t)d << 12);
                            int k = 1, run = 1;
                            if (b == a) { ++run; k *= run; } else run = 1;
                            if (c == b) { ++run; k *= run; } else run = 1;
                            if (d == c) { ++run; k *= run; } else run = 1;
                            rk = 1.0f / (float)k;
                        }
                        done = true; break;
                    }
                    base += L;
                }
        }
        fd[t] = f; rkA[t] = rk;
        return;
    }
    id -= TPAD;
    if (id < NQ) {                       // quad descriptors: off1 | off2_0<<8
        int t0 = id * 4;
        uint32_t o1 = 0, o2 = 0;
        if (t0 < 16) {
            o1 = 0; o2 = (uint32_t)t0;
        } else if (t0 < BASE3) {
            int base = BASE2;
            for (int a = 0; a < 12; ++a) {
                int L = ceil4(12 - a);
                if (t0 < base + L) { o1 = 1 + a; o2 = 1 + a + (t0 - base); break; }
                base += L;
            }
        } else if (t0 < BASE4) {
            int base = BASE3; bool done = false;
            for (int a = 0; a < 12 && !done; ++a)
                for (int b = a; b < 12; ++b) {
                    int L = ceil4(12 - b);
                    if (t0 < base + L) {
                        o1 = 13 + rank2(a, b); o2 = 1 + b + (t0 - base);
                        done = true; break;
                    }
                    base += L;
                }
        } else if (t0 < TEND) {
            int base = BASE4; bool done = false;
            for (int a = 0; a < 12 && !done; ++a)
                for (int b = a; b < 12; ++b) {
                    int L = ceil4(H2f(12 - b));
                    if (t0 < base + L) {
                        o1 = 13 + rank2(a, b);
                        o2 = 13 + rank2(b, b) + (t0 - base);
                        done = true; break;
                    }
                    base += L;
                }
        }
        qd[id] = o1 | (o2 << 8);
        return;
    }
    id -= NQ;
    if (id < 78) {                       // deg2 msm build pairs
        int r = id;
        int a = 0; while (r >= (NI - a)) { r -= (NI - a); ++a; }
        int b = a + r;
        mq2[id] = (uint32_t)(1 + a) | ((uint32_t)(1 + b) << 16);
    }
}

// ---------- fold: stage weight row in LDS (f32), per-t orbit gather ----------
// One block (1024 threads) per o. Wh fp16 pack-of-8: [((t>>3)*512+o)*8+(t&7)].
__global__ __launch_bounds__(1024) void pinet_fold(
    const float* __restrict__ w0, const float* __restrict__ w1,
    const float* __restrict__ w2, const float* __restrict__ w3,
    const float* __restrict__ w4,
    const uint32_t* __restrict__ fd, const float* __restrict__ rkA,
    ushort* __restrict__ Wh) {
    __shared__ float sw4[20736];
    __shared__ float sw3[1728];
    __shared__ float sw2[144];
    const int tid = threadIdx.x;
    const int o = blockIdx.x;

    {   // coalesced staging
        const float4* g4 = (const float4*)(w4 + o * 20736);
        float4* s4 = (float4*)sw4;
        for (int i = tid; i < 5184; i += 1024) s4[i] = g4[i];
        if (tid < 432) ((float4*)sw3)[tid] = ((const float4*)(w3 + o * 1728))[tid];
        if (tid < 36)  ((float4*)sw2)[tid] = ((const float4*)(w2 + o * 144))[tid];
    }
    __syncthreads();

#define W4P(p, q, r, s_) sw4[(p) * 1728 + (q) * 144 + (r) * 12 + (s_)]
#define W3P(p, q, r)     sw3[(p) * 144 + (q) * 12 + (r)]
    for (int t = tid; t < TPAD; t += 1024) {
        uint32_t f = fd[t];
        int deg = (f >> 16) & 7;
        int a = f & 15, b = (f >> 4) & 15, c = (f >> 8) & 15, d = (f >> 12) & 15;
        float s = 0.0f;
        if (deg == 0) {
            s = w0[o];
        } else if (deg == 1) {
            s = w1[o * 12 + a];
        } else if (deg == 2) {
            s = (sw2[a * 12 + b] + sw2[b * 12 + a]) * rkA[t];
        } else if (deg == 3) {
            s = (W3P(a, b, c) + W3P(a, c, b) + W3P(b, a, c) +
                 W3P(b, c, a) + W3P(c, a, b) + W3P(c, b, a)) * rkA[t];
        } else if (deg == 4) {
            float s4v =
                W4P(a,b,c,d) + W4P(a,b,d,c) + W4P(a,c,b,d) + W4P(a,c,d,b) +
                W4P(a,d,b,c) + W4P(a,d,c,b) + W4P(b,a,c,d) + W4P(b,a,d,c) +
                W4P(b,c,a,d) + W4P(b,c,d,a) + W4P(b,d,a,c) + W4P(b,d,c,a) +
                W4P(c,a,b,d) + W4P(c,a,d,b) + W4P(c,b,a,d) + W4P(c,b,d,a) +
                W4P(c,d,a,b) + W4P(c,d,b,a) + W4P(d,a,b,c) + W4P(d,a,c,b) +
                W4P(d,b,a,c) + W4P(d,b,c,a) + W4P(d,c,a,b) + W4P(d,c,b,a);
            s = s4v * rkA[t];
        }
        Wh[((t >> 3) * NO + o) * 8 + (t & 7)] = f2h(s);
    }
#undef W4P
#undef W3P
}

// ---------- MFMA GEMM: out[b,o] = sum_t M[t][b] * Wt[t][o], fp16 ----------
// Block: 32 b x 256 o, 256 threads (4 waves, each 32b x 64o -- no wB dup).
// Grid 512 = 2 blocks/CU: two independent barrier domains overlap pipes.
__global__ __launch_bounds__(256) void pinet_gemm(
    const float* __restrict__ x, const ushort* __restrict__ Wh,
    const uint32_t* __restrict__ qd, const uint32_t* __restrict__ mq2,
    float* __restrict__ out) {
    __shared__ float msm[32 * 97];        // per-b {1, x0..x11, 78 deg2, 6 zero}
    __shared__ ushort Ash[2][32][8][8];   // [buf][b][t-oct slot (swz)][8 fp16]
    __shared__ uint32_t qd_sh[NQ];

    const int tid = threadIdx.x;
    const int b0 = (blockIdx.x >> 1) * 32;
    const int blkO = blockIdx.x & 1;

    // phase 1: constants, x, zero-pad
    for (int idx = tid; idx < 32 * 12; idx += 256) {
        int b = idx / 12, j = idx % 12;
        msm[b * 97 + 1 + j] = x[(b0 + b) * 12 + j];
    }
    if (tid < 32) msm[tid * 97] = 1.0f;
    if (tid >= 64 && tid < 256) {
        int idx = tid - 64;               // 32*6 = 192 zero slots
        int b = idx / 6, j = idx % 6;
        msm[b * 97 + 91 + j] = 0.0f;
    }
    for (int i = tid; i < NQ; i += 256) qd_sh[i] = qd[i];
    __syncthreads();
    // phase 2: deg2 products
    for (int idx = tid; idx < 32 * 78; idx += 256) {
        int b = idx / 78, q = idx % 78;
        uint32_t m2 = mq2[q];
        msm[b * 97 + 13 + q] = msm[b * 97 + (m2 & 0xFFFFu)] *
                               msm[b * 97 + (m2 >> 16)];
    }

    const int l = tid & 63, wv = tid >> 6;       // 4 waves
    const int lm = l & 15, lg = l >> 4;
    const int o_w = blkO * 256 + wv * 64;
    const int gb = tid & 31, qs2 = tid >> 5;     // gen: b x quad-slot (0..7)

    f32x4 acc[2][4] = {};                        // [bs][os]
    f16x8 B0[2][4], B1[2][4];                    // [c][os]

    auto gen = [&](int kt, int buf) {
        const float* row = &msm[gb * 97];
#pragma unroll
        for (int jj = 0; jj < 2; ++jj) {
            const int qs = qs2 + jj * 8;         // wave-uniform
            uint32_t dsc = qd_sh[kt * 16 + qs];
            int o1 = dsc & 0xFFu, o2 = (dsc >> 8) & 0xFFu;
            float m1 = row[o1];
            float p0 = m1 * row[o2 + 0];
            float p1 = m1 * row[o2 + 1];
            float p2 = m1 * row[o2 + 2];
            float p3 = m1 * row[o2 + 3];
            ushort4 v = {f2h(p0), f2h(p1), f2h(p2), f2h(p3)};
            *(ushort4*)&Ash[buf][gb][(qs >> 1) ^ (gb & 7)][(qs & 1) * 4] = v;
        }
    };
    auto loadB = [&](int kt, f16x8 (&B)[2][4]) {
#pragma unroll
        for (int c = 0; c < 2; ++c)
#pragma unroll
            for (int os = 0; os < 4; ++os) {
                int pk = kt * 8 + c * 4 + lg;
                B[c][os] = *(const f16x8*)
                    (Wh + ((size_t)pk * NO + o_w + os * 16 + lm) * 8);
            }
    };
    auto mfmaR = [&](int cur, f16x8 (&B)[2][4]) {
#pragma unroll
        for (int c = 0; c < 2; ++c) {
            int br0 = lm, br1 = 16 + lm;
            f16x8 a0 = *(const f16x8*)&Ash[cur][br0][(c * 4 + lg) ^ (br0 & 7)][0];
            f16x8 a1 = *(const f16x8*)&Ash[cur][br1][(c * 4 + lg) ^ (br1 & 7)][0];
#pragma unroll
            for (int os = 0; os < 4; ++os) {
                acc[0][os] = MFMA16(a0, B[c][os], acc[0][os]);
                acc[1][os] = MFMA16(a1, B[c][os], acc[1][os]);
            }
        }
    };

    __syncthreads();          // msm ready
    gen(0, 0);
    loadB(0, B0);
    __syncthreads();          // Ash[0] ready

    for (int kt2 = 0; kt2 < NKT - 1; kt2 += 2) {
        loadB(kt2 + 1, B1);
        gen(kt2 + 1, 1);
        mfmaR(0, B0);
        __syncthreads();
        loadB(kt2 + 2, B0);   // kt2+2 <= 32 = NKT-1, always valid
        gen(kt2 + 2, 0);
        mfmaR(1, B1);
        __syncthreads();
    }
    mfmaR(0, B0);             // kt = 32 (buf 0)

#pragma unroll
    for (int bs = 0; bs < 2; ++bs)
#pragma unroll
        for (int os = 0; os < 4; ++os) {
            int ob = o_w + os * 16 + lm;
#pragma unroll
            for (int r = 0; r < 4; ++r) {
                int bb = b0 + bs * 16 + lg * 4 + r;
                out[bb * NO + ob] = acc[bs][os][r];
            }
        }
}

extern "C" void kernel_launch(void* const* d_in, const int* in_sizes, int n_in,
                              void* d_out, int out_size, void* d_ws, size_t ws_size,
                              hipStream_t stream) {
    const float* x  = (const float*)d_in[0];
    const float* w0 = (const float*)d_in[1];
    const float* w1 = (const float*)d_in[2];
    const float* w2 = (const float*)d_in[3];
    const float* w3 = (const float*)d_in[4];
    const float* w4 = (const float*)d_in[5];
    float* out = (float*)d_out;

    uint8_t* ws = (uint8_t*)d_ws;
    uint32_t* qd  = (uint32_t*)ws;                 // 2112 B  (pad 4096)
    uint32_t* mq2 = (uint32_t*)(ws + 4096);        // 312 B   (pad 512)
    uint32_t* fd  = (uint32_t*)(ws + 4608);        // 8448 B  (pad 8704)
    float*    rkA = (float*)(ws + 13312);          // 8448 B  (pad 8704)
    ushort*   Wh  = (ushort*)(ws + 22016);         // 264*512*8*2 = 2,162,688 B

    pinet_maps<<<11, 256, 0, stream>>>(fd, rkA, qd, mq2);
    pinet_fold<<<NO, 1024, 0, stream>>>(w0, w1, w2, w3, w4, fd, rkA, Wh);
    pinet_gemm<<<(NB / 32) * 2, 256, 0, stream>>>(x, Wh, qd, mq2, out);
}